// Round 6
// baseline (461.115 us; speedup 1.0000x reference)
//
#include <hip/hip_runtime.h>
#include <math.h>

#define F_IN 256
#define HID  64
#define BSH  8              // bucket = dst >> 8 (256 nodes per bucket)
#define BSPAN 256
#define CHUNK 16384         // edges per sort block (64 per thread)
#define NBK_MAX 512

typedef __bf16 bf16x8 __attribute__((ext_vector_type(8)));
typedef float  floatx4 __attribute__((ext_vector_type(4)));

// ---------------------------------------------------------------------------
// Pass 1: per-chunk histogram over coarse dst buckets
// ---------------------------------------------------------------------------
__global__ __launch_bounds__(256) void k_hist(const int* __restrict__ dst,
                                              int* __restrict__ cntT,
                                              int E, int NCH, int NBK) {
    __shared__ int hist[NBK_MAX];
    int t = threadIdx.x, c = blockIdx.x;
    hist[t] = 0; hist[t + 256] = 0;
    __syncthreads();
    int base = c * CHUNK;
#pragma unroll 4
    for (int j = 0; j < CHUNK / 256; j++) {
        int e = base + j * 256 + t;
        if (e < E) atomicAdd(&hist[dst[e] >> BSH], 1);
    }
    __syncthreads();
    for (int b = t; b < NBK; b += 256) cntT[b * NCH + c] = hist[b];
}

// ---------------------------------------------------------------------------
// Exclusive scan of cntT (S elements) -> off, plus sentinel off[S] = total
// ---------------------------------------------------------------------------
__global__ __launch_bounds__(256) void k_scanA(const int* __restrict__ cntT,
                                               int* __restrict__ off,
                                               int* __restrict__ partials, int S) {
    __shared__ int sh[256];
    int tid = threadIdx.x;
    int base = blockIdx.x * 1024 + tid * 4;
    int v[4];
    int s = 0;
#pragma unroll
    for (int j = 0; j < 4; j++) {
        int idx = base + j;
        v[j] = (idx < S) ? cntT[idx] : 0;
        s += v[j];
    }
    sh[tid] = s;
    __syncthreads();
    int mysum = s;
    for (int o = 1; o < 256; o <<= 1) {
        int tv = (tid >= o) ? sh[tid - o] : 0;
        __syncthreads();
        sh[tid] += tv;
        __syncthreads();
    }
    int pref = sh[tid] - mysum;
#pragma unroll
    for (int j = 0; j < 4; j++) {
        int idx = base + j;
        if (idx < S) off[idx] = pref;
        pref += v[j];
    }
    if (tid == 255) partials[blockIdx.x] = sh[255];
}

__global__ void k_scanB(int* __restrict__ partials, int* __restrict__ off,
                        int nblk, int S) {
    if (blockIdx.x == 0 && threadIdx.x == 0) {
        int run = 0;
        for (int b = 0; b < nblk; b++) { int t = partials[b]; partials[b] = run; run += t; }
        off[S] = run;   // == E
    }
}

__global__ void k_scanC(int* __restrict__ off, const int* __restrict__ partials, int S) {
    int i = blockIdx.x * blockDim.x + threadIdx.x;
    if (i < S) off[i] += partials[i >> 10];
}

// ---------------------------------------------------------------------------
// Pass 2: scatter edges into bucket-grouped ebuf. Entry = (src<<8)|(dst&255)
// ---------------------------------------------------------------------------
__global__ __launch_bounds__(256) void k_sortwrite(const int* __restrict__ src,
                                                   const int* __restrict__ dst,
                                                   const int* __restrict__ off,
                                                   int* __restrict__ ebuf,
                                                   int E, int NCH, int NBK) {
    __shared__ int cur[NBK_MAX];
    int t = threadIdx.x, c = blockIdx.x;
    for (int b = t; b < NBK; b += 256) cur[b] = off[b * NCH + c];
    __syncthreads();
    int base = c * CHUNK;
#pragma unroll 4
    for (int j = 0; j < CHUNK / 256; j++) {
        int e = base + j * 256 + t;
        if (e < E) {
            int s = src[e];
            int d = dst[e];
            int pos = atomicAdd(&cur[d >> BSH], 1);
            ebuf[pos] = (s << BSH) | (d & (BSPAN - 1));
        }
    }
}

// ---------------------------------------------------------------------------
// Pass 3: per-bucket node-level CSR: rp, dinv, node-sorted esrc
// ---------------------------------------------------------------------------
__global__ __launch_bounds__(256) void k_bucket_csr(const int* __restrict__ off,
                                                    const int* __restrict__ ebuf,
                                                    int* __restrict__ rp,
                                                    float* __restrict__ dinv,
                                                    int* __restrict__ esrc,
                                                    int N, int NCH, int NBK) {
    __shared__ int cnt[BSPAN];
    __shared__ int sh[BSPAN];
    int b = blockIdx.x, t = threadIdx.x;
    int base = off[b * NCH];
    int end  = off[(b + 1) * NCH];

    cnt[t] = 0;
    __syncthreads();
    for (int i = base + t; i < end; i += 256) atomicAdd(&cnt[ebuf[i] & (BSPAN - 1)], 1);
    __syncthreads();

    int c = cnt[t];
    sh[t] = c;
    __syncthreads();
    for (int o = 1; o < 256; o <<= 1) {
        int tv = (t >= o) ? sh[t - o] : 0;
        __syncthreads();
        sh[t] += tv;
        __syncthreads();
    }
    int excl = sh[t] - c;

    int node = (b << BSH) + t;
    if (node < N) {
        rp[node] = base + excl;
        dinv[node] = rsqrtf((float)(1 + c));
    }
    if (b == NBK - 1 && t == 0) rp[N] = end;
    __syncthreads();

    cnt[t] = base + excl;
    __syncthreads();
    for (int i = base + t; i < end; i += 256) {
        int v = ebuf[i];
        int p = atomicAdd(&cnt[v & (BSPAN - 1)], 1);
        esrc[p] = v >> BSH;
    }
}

// ---------------------------------------------------------------------------
// One-time weight prep: W[K x 64] -> transposed split-bf16 Bt_hi/Bt_lo [64 x K]
// ---------------------------------------------------------------------------
__global__ __launch_bounds__(256) void k_prepw(const float* __restrict__ W1,
                                               __bf16* __restrict__ w1h, __bf16* __restrict__ w1l,
                                               const float* __restrict__ W2,
                                               __bf16* __restrict__ w2h, __bf16* __restrict__ w2l) {
    int t = threadIdx.x + blockIdx.x * blockDim.x;
    for (int idx = t; idx < 64 * 256; idx += 256 * 8) {
        int c = idx >> 8, k = idx & 255;
        float w = W1[k * 64 + c];
        __bf16 h = (__bf16)w;
        w1h[idx] = h;
        w1l[idx] = (__bf16)(w - (float)h);
    }
    for (int idx = t; idx < 64 * 64; idx += 256 * 8) {
        int c = idx >> 6, k = idx & 63;
        float w = W2[k * 64 + c];
        __bf16 h = (__bf16)w;
        w2h[idx] = h;
        w2l[idx] = (__bf16)(w - (float)h);
    }
}

// ---------------------------------------------------------------------------
// Split-bf16 MFMA GEMM: C[nrows x 64] = (A[nrows x K] @ B[K x 64]) * dinv[row]
// Fully unrolled K; ALL A loads hoisted up front (deep MLP, one latency
// exposure). B pre-split transposed bf16 [64 x K], L1/L2-hot.
//   D = Ah*Bh + Ah*Bl + Al*Bh   (Al*Bl ~2^-18 dropped)
// mfma_f32_16x16x32_bf16 layouts (HW-verified): A[m=lane&15][k=q*8+j],
// Bt[n=lane&15][k=q*8+j], C/D: col=lane&15, row=q*4+reg.
// ---------------------------------------------------------------------------
template <int K>
__global__ __launch_bounds__(256) void k_gemm_mfma(const float* __restrict__ A,
                                                   const __bf16* __restrict__ BtH,
                                                   const __bf16* __restrict__ BtL,
                                                   const float* __restrict__ dinv,
                                                   float* __restrict__ C, int nrows) {
    constexpr int NCK = K / 32;
    int wave = threadIdx.x >> 6;
    int lane = threadIdx.x & 63;
    int m = lane & 15;
    int q = lane >> 4;
    int row0 = blockIdx.x * 64 + wave * 16;
    int arow = row0 + m;
    bool rvalid = arow < nrows;
    const float* ap = A + (size_t)arow * K + q * 8;

    // hoist ALL A loads — independent, all in flight simultaneously
    float4 fa[NCK][2];
#pragma unroll
    for (int ch = 0; ch < NCK; ch++) {
        fa[ch][0] = make_float4(0.f, 0.f, 0.f, 0.f);
        fa[ch][1] = make_float4(0.f, 0.f, 0.f, 0.f);
        if (rvalid) {
            fa[ch][0] = *(const float4*)(ap + ch * 32);
            fa[ch][1] = *(const float4*)(ap + ch * 32 + 4);
        }
    }

    floatx4 acc[4] = {{0.f, 0.f, 0.f, 0.f}, {0.f, 0.f, 0.f, 0.f},
                      {0.f, 0.f, 0.f, 0.f}, {0.f, 0.f, 0.f, 0.f}};

#pragma unroll
    for (int ch = 0; ch < NCK; ch++) {
        float af[8] = {fa[ch][0].x, fa[ch][0].y, fa[ch][0].z, fa[ch][0].w,
                       fa[ch][1].x, fa[ch][1].y, fa[ch][1].z, fa[ch][1].w};
        bf16x8 ah, al;
#pragma unroll
        for (int j = 0; j < 8; j++) {
            __bf16 h = (__bf16)af[j];
            ah[j] = h;
            al[j] = (__bf16)(af[j] - (float)h);
        }
#pragma unroll
        for (int c = 0; c < 4; c++) {
            const __bf16* bp = BtH + (size_t)(c * 16 + m) * K + ch * 32 + q * 8;
            const __bf16* bq = BtL + (size_t)(c * 16 + m) * K + ch * 32 + q * 8;
            bf16x8 bh = *(const bf16x8*)bp;
            bf16x8 bl = *(const bf16x8*)bq;
            acc[c] = __builtin_amdgcn_mfma_f32_16x16x32_bf16(ah, bh, acc[c], 0, 0, 0);
            acc[c] = __builtin_amdgcn_mfma_f32_16x16x32_bf16(al, bh, acc[c], 0, 0, 0);
            acc[c] = __builtin_amdgcn_mfma_f32_16x16x32_bf16(ah, bl, acc[c], 0, 0, 0);
        }
    }

#pragma unroll
    for (int i = 0; i < 4; i++) {
        int r = row0 + q * 4 + i;
        if (r < nrows) {
            float di = dinv[r];
#pragma unroll
            for (int c = 0; c < 4; c++)
                C[(size_t)r * 64 + c * 16 + m] = acc[c][i] * di;
        }
    }
}

// ---------------------------------------------------------------------------
// Aggregation over CSR, 64 features, one wave per node, 8-deep MLP.
// ---------------------------------------------------------------------------
template <int MODE>
__global__ __launch_bounds__(256) void k_agg64(const float* __restrict__ hs,
                                               const float* __restrict__ dinv,
                                               const int* __restrict__ rp,
                                               const int* __restrict__ esrc,
                                               const float* __restrict__ bias,
                                               const float* __restrict__ W3,
                                               float* __restrict__ out, int n) {
    int lane = threadIdx.x & 63;
    int nid = blockIdx.x * 4 + (threadIdx.x >> 6);
    if (nid >= n) return;
    nid = __builtin_amdgcn_readfirstlane(nid);

    float dii = dinv[nid];
    int e0 = rp[nid];
    int e1 = rp[nid + 1];

    float a0 = hs[(size_t)nid * 64 + lane];
    float a1 = 0.f, a2 = 0.f, a3 = 0.f, a4 = 0.f, a5 = 0.f, a6 = 0.f, a7 = 0.f;

    for (int e = e0; e < e1; e += 8) {
        int last = e1 - 1;
        int i0 = esrc[e];
        int i1 = esrc[min(e + 1, last)];
        int i2 = esrc[min(e + 2, last)];
        int i3 = esrc[min(e + 3, last)];
        int i4 = esrc[min(e + 4, last)];
        int i5 = esrc[min(e + 5, last)];
        int i6 = esrc[min(e + 6, last)];
        int i7 = esrc[min(e + 7, last)];
        float v0 = hs[(size_t)i0 * 64 + lane];
        float v1 = hs[(size_t)i1 * 64 + lane];
        float v2 = hs[(size_t)i2 * 64 + lane];
        float v3 = hs[(size_t)i3 * 64 + lane];
        float v4 = hs[(size_t)i4 * 64 + lane];
        float v5 = hs[(size_t)i5 * 64 + lane];
        float v6 = hs[(size_t)i6 * 64 + lane];
        float v7 = hs[(size_t)i7 * 64 + lane];
        a0 += v0;
        a1 += (e + 1 <= last) ? v1 : 0.f;
        a2 += (e + 2 <= last) ? v2 : 0.f;
        a3 += (e + 3 <= last) ? v3 : 0.f;
        a4 += (e + 4 <= last) ? v4 : 0.f;
        a5 += (e + 5 <= last) ? v5 : 0.f;
        a6 += (e + 6 <= last) ? v6 : 0.f;
        a7 += (e + 7 <= last) ? v7 : 0.f;
    }

    float acc = ((a0 + a1) + (a2 + a3)) + ((a4 + a5) + (a6 + a7));
    acc = acc * dii + bias[lane];
    acc = fmaxf(acc, 0.f);

    if (MODE == 0) {
        out[(size_t)nid * 64 + lane] = acc;
    } else {
        float2 w3 = ((const float2*)W3)[lane];
        float p0 = acc * w3.x;
        float p1 = acc * w3.y;
#pragma unroll
        for (int o = 32; o > 0; o >>= 1) {
            p0 += __shfl_xor(p0, o, 64);
            p1 += __shfl_xor(p1, o, 64);
        }
        if (lane == 0) ((float2*)out)[nid] = make_float2(p0 * dii, p1 * dii);
    }
}

// ---------------------------------------------------------------------------
// Final layer: 2-wide aggregation + bias + log_softmax (thread per node)
// ---------------------------------------------------------------------------
__global__ __launch_bounds__(256) void k_final(const float2* __restrict__ h3s,
                                               const float* __restrict__ dinv,
                                               const int* __restrict__ rp,
                                               const int* __restrict__ esrc,
                                               const float* __restrict__ b3,
                                               float* __restrict__ out, int n) {
    int i = blockIdx.x * blockDim.x + threadIdx.x;
    if (i >= n) return;
    float dii = dinv[i];
    float2 h = h3s[i];
    float ax = h.x, ay = h.y;
    float bx = 0.f, by = 0.f, cx = 0.f, cy = 0.f, dx = 0.f, dy = 0.f;
    int e0 = rp[i], e1 = rp[i + 1];
    for (int e = e0; e < e1; e += 4) {
        int last = e1 - 1;
        int s0 = esrc[e];
        int s1 = esrc[min(e + 1, last)];
        int s2 = esrc[min(e + 2, last)];
        int s3 = esrc[min(e + 3, last)];
        float2 v0 = h3s[s0];
        float2 v1 = h3s[s1];
        float2 v2 = h3s[s2];
        float2 v3 = h3s[s3];
        ax += v0.x; ay += v0.y;
        bx += (e + 1 <= last) ? v1.x : 0.f; by += (e + 1 <= last) ? v1.y : 0.f;
        cx += (e + 2 <= last) ? v2.x : 0.f; cy += (e + 2 <= last) ? v2.y : 0.f;
        dx += (e + 3 <= last) ? v3.x : 0.f; dy += (e + 3 <= last) ? v3.y : 0.f;
    }
    float l0 = ((ax + bx) + (cx + dx)) * dii + b3[0];
    float l1 = ((ay + by) + (cy + dy)) * dii + b3[1];
    float m = fmaxf(l0, l1);
    float lse = m + logf(expf(l0 - m) + expf(l1 - m));
    ((float2*)out)[i] = make_float2(l0 - lse, l1 - lse);
}

// ---------------------------------------------------------------------------
// Launch
// ---------------------------------------------------------------------------
extern "C" void kernel_launch(void* const* d_in, const int* in_sizes, int n_in,
                              void* d_out, int out_size, void* d_ws, size_t ws_size,
                              hipStream_t stream) {
    const float* x   = (const float*)d_in[0];
    const int*   ei  = (const int*)d_in[1];
    const float* W1  = (const float*)d_in[2];
    const float* b1  = (const float*)d_in[3];
    const float* W2  = (const float*)d_in[4];
    const float* b2  = (const float*)d_in[5];
    const float* W3  = (const float*)d_in[6];
    const float* b3  = (const float*)d_in[7];
    float* out = (float*)d_out;

    const int N = in_sizes[0] / F_IN;   // 100000
    const int E = in_sizes[1] / 2;      // 1600000
    const int* src = ei;
    const int* dst = ei + E;

    const int NBK = (N + BSPAN - 1) / BSPAN;      // 391
    const int NCH = (E + CHUNK - 1) / CHUNK;      // 98
    const int S   = NBK * NCH;

    // workspace bump allocator (256B aligned)
    char* p = (char*)d_ws;
    auto alloc = [&](size_t bytes) -> void* {
        void* r = (void*)p;
        p += (bytes + 255) & ~(size_t)255;
        return r;
    };
    int*    cntT     = (int*)alloc((size_t)S * 4);
    int*    off      = (int*)alloc((size_t)(S + 1) * 4);
    int*    partials = (int*)alloc(4096);
    int*    ebuf     = (int*)alloc((size_t)E * 4);
    int*    esrc     = (int*)alloc((size_t)E * 4);
    int*    rp       = (int*)alloc((size_t)(N + 1) * 4);
    float*  dinv     = (float*)alloc((size_t)N * 4);
    float*  bufA     = (float*)alloc((size_t)N * HID * 4);
    float*  bufB     = (float*)alloc((size_t)N * HID * 4);
    float*  h3       = (float*)alloc((size_t)N * 2 * 4);
    __bf16* w1h      = (__bf16*)alloc(64 * 256 * 2);
    __bf16* w1l      = (__bf16*)alloc(64 * 256 * 2);
    __bf16* w2h      = (__bf16*)alloc(64 * 64 * 2);
    __bf16* w2l      = (__bf16*)alloc(64 * 64 * 2);

    const int T = 256;
    int scanBlocks = (S + 1023) / 1024;

    // weight prep (independent of CSR chain)
    k_prepw<<<8, T, 0, stream>>>(W1, w1h, w1l, W2, w2h, w2l);

    // CSR build via locality-aware counting sort
    k_hist<<<NCH, T, 0, stream>>>(dst, cntT, E, NCH, NBK);
    k_scanA<<<scanBlocks, T, 0, stream>>>(cntT, off, partials, S);
    k_scanB<<<1, 64, 0, stream>>>(partials, off, scanBlocks, S);
    k_scanC<<<(S + T - 1) / T, T, 0, stream>>>(off, partials, S);
    k_sortwrite<<<NCH, T, 0, stream>>>(src, dst, off, ebuf, E, NCH, NBK);
    k_bucket_csr<<<NBK, T, 0, stream>>>(off, ebuf, rp, dinv, esrc, N, NCH, NBK);

    // layer 1
    int gemmBlocks = (N + 63) / 64;
    k_gemm_mfma<F_IN><<<gemmBlocks, T, 0, stream>>>(x, w1h, w1l, dinv, bufA, N);
    k_agg64<0><<<(N + 3) / 4, T, 0, stream>>>(bufA, dinv, rp, esrc, b1, nullptr, bufB, N);

    // layer 2 (+ fused GEMM3)
    k_gemm_mfma<HID><<<gemmBlocks, T, 0, stream>>>(bufB, w2h, w2l, dinv, bufA, N);
    k_agg64<1><<<(N + 3) / 4, T, 0, stream>>>(bufA, dinv, rp, esrc, b2, W3, h3, N);

    // layer 3 + log_softmax
    k_final<<<(N + T - 1) / T, T, 0, stream>>>((const float2*)h3, dinv, rp, esrc, b3, out, N);
}

// Round 7
// 414.889 us; speedup vs baseline: 1.1114x; 1.1114x over previous
//
#include <hip/hip_runtime.h>
#include <math.h>

#define F_IN 256
#define HID  64
#define BSH  8              // bucket = dst >> 8 (256 nodes per bucket)
#define BSPAN 256
#define CHUNK 16384         // edges per sort block (64 per thread)
#define NBK_MAX 512

typedef __bf16 bf16x8 __attribute__((ext_vector_type(8)));
typedef float  floatx4 __attribute__((ext_vector_type(4)));

// ---------------------------------------------------------------------------
// Pass 1: per-chunk histogram over coarse dst buckets
// ---------------------------------------------------------------------------
__global__ __launch_bounds__(256) void k_hist(const int* __restrict__ dst,
                                              int* __restrict__ cntT,
                                              int E, int NCH, int NBK) {
    __shared__ int hist[NBK_MAX];
    int t = threadIdx.x, c = blockIdx.x;
    hist[t] = 0; hist[t + 256] = 0;
    __syncthreads();
    int base = c * CHUNK;
#pragma unroll 4
    for (int j = 0; j < CHUNK / 256; j++) {
        int e = base + j * 256 + t;
        if (e < E) atomicAdd(&hist[dst[e] >> BSH], 1);
    }
    __syncthreads();
    for (int b = t; b < NBK; b += 256) cntT[b * NCH + c] = hist[b];
}

// ---------------------------------------------------------------------------
// Exclusive scan of cntT (S elements) -> off, plus sentinel off[S] = total
// ---------------------------------------------------------------------------
__global__ __launch_bounds__(256) void k_scanA(const int* __restrict__ cntT,
                                               int* __restrict__ off,
                                               int* __restrict__ partials, int S) {
    __shared__ int sh[256];
    int tid = threadIdx.x;
    int base = blockIdx.x * 1024 + tid * 4;
    int v[4];
    int s = 0;
#pragma unroll
    for (int j = 0; j < 4; j++) {
        int idx = base + j;
        v[j] = (idx < S) ? cntT[idx] : 0;
        s += v[j];
    }
    sh[tid] = s;
    __syncthreads();
    int mysum = s;
    for (int o = 1; o < 256; o <<= 1) {
        int tv = (tid >= o) ? sh[tid - o] : 0;
        __syncthreads();
        sh[tid] += tv;
        __syncthreads();
    }
    int pref = sh[tid] - mysum;
#pragma unroll
    for (int j = 0; j < 4; j++) {
        int idx = base + j;
        if (idx < S) off[idx] = pref;
        pref += v[j];
    }
    if (tid == 255) partials[blockIdx.x] = sh[255];
}

__global__ void k_scanB(int* __restrict__ partials, int* __restrict__ off,
                        int nblk, int S) {
    if (blockIdx.x == 0 && threadIdx.x == 0) {
        int run = 0;
        for (int b = 0; b < nblk; b++) { int t = partials[b]; partials[b] = run; run += t; }
        off[S] = run;   // == E
    }
}

__global__ void k_scanC(int* __restrict__ off, const int* __restrict__ partials, int S) {
    int i = blockIdx.x * blockDim.x + threadIdx.x;
    if (i < S) off[i] += partials[i >> 10];
}

// ---------------------------------------------------------------------------
// Pass 2: scatter edges into bucket-grouped ebuf. Entry = (src<<8)|(dst&255)
// ---------------------------------------------------------------------------
__global__ __launch_bounds__(256) void k_sortwrite(const int* __restrict__ src,
                                                   const int* __restrict__ dst,
                                                   const int* __restrict__ off,
                                                   int* __restrict__ ebuf,
                                                   int E, int NCH, int NBK) {
    __shared__ int cur[NBK_MAX];
    int t = threadIdx.x, c = blockIdx.x;
    for (int b = t; b < NBK; b += 256) cur[b] = off[b * NCH + c];
    __syncthreads();
    int base = c * CHUNK;
#pragma unroll 4
    for (int j = 0; j < CHUNK / 256; j++) {
        int e = base + j * 256 + t;
        if (e < E) {
            int s = src[e];
            int d = dst[e];
            int pos = atomicAdd(&cur[d >> BSH], 1);
            ebuf[pos] = (s << BSH) | (d & (BSPAN - 1));
        }
    }
}

// ---------------------------------------------------------------------------
// Pass 3: per-bucket node-level CSR: rp, dinv, node-sorted esrc
// ---------------------------------------------------------------------------
__global__ __launch_bounds__(256) void k_bucket_csr(const int* __restrict__ off,
                                                    const int* __restrict__ ebuf,
                                                    int* __restrict__ rp,
                                                    float* __restrict__ dinv,
                                                    int* __restrict__ esrc,
                                                    int N, int NCH, int NBK) {
    __shared__ int cnt[BSPAN];
    __shared__ int sh[BSPAN];
    int b = blockIdx.x, t = threadIdx.x;
    int base = off[b * NCH];
    int end  = off[(b + 1) * NCH];

    cnt[t] = 0;
    __syncthreads();
    for (int i = base + t; i < end; i += 256) atomicAdd(&cnt[ebuf[i] & (BSPAN - 1)], 1);
    __syncthreads();

    int c = cnt[t];
    sh[t] = c;
    __syncthreads();
    for (int o = 1; o < 256; o <<= 1) {
        int tv = (t >= o) ? sh[t - o] : 0;
        __syncthreads();
        sh[t] += tv;
        __syncthreads();
    }
    int excl = sh[t] - c;

    int node = (b << BSH) + t;
    if (node < N) {
        rp[node] = base + excl;
        dinv[node] = rsqrtf((float)(1 + c));
    }
    if (b == NBK - 1 && t == 0) rp[N] = end;
    __syncthreads();

    cnt[t] = base + excl;
    __syncthreads();
    for (int i = base + t; i < end; i += 256) {
        int v = ebuf[i];
        int p = atomicAdd(&cnt[v & (BSPAN - 1)], 1);
        esrc[p] = v >> BSH;
    }
}

// ---------------------------------------------------------------------------
// Weight prep: W[K x 64] -> split-bf16 MFMA FRAGMENT layout
//   Bf[c][ch2][lane][j] = W[ch2*32 + (lane>>4)*8 + j][c*16 + (lane&15)]
// so each wave's B-frag load is a contiguous 1 KB (16 B/lane), L1-resident.
// ---------------------------------------------------------------------------
__global__ __launch_bounds__(256) void k_prepw(const float* __restrict__ W1,
                                               __bf16* __restrict__ f1h, __bf16* __restrict__ f1l,
                                               const float* __restrict__ W2,
                                               __bf16* __restrict__ f2h, __bf16* __restrict__ f2l) {
    int t = threadIdx.x + blockIdx.x * blockDim.x;   // 2048 threads
    // W1: K=256 -> 4 c * 8 ch2 * 64 lane * 8 j = 16384
    for (int idx = t; idx < 16384; idx += 2048) {
        int j = idx & 7, lane = (idx >> 3) & 63, ch2 = (idx >> 9) & 7, c = idx >> 12;
        int k = ch2 * 32 + (lane >> 4) * 8 + j, col = c * 16 + (lane & 15);
        float w = W1[k * 64 + col];
        __bf16 h = (__bf16)w;
        f1h[idx] = h; f1l[idx] = (__bf16)(w - (float)h);
    }
    // W2: K=64 -> 4 c * 2 ch2 * 64 lane * 8 j = 4096
    for (int idx = t; idx < 4096; idx += 2048) {
        int j = idx & 7, lane = (idx >> 3) & 63, ch2 = (idx >> 9) & 1, c = idx >> 10;
        int k = ch2 * 32 + (lane >> 4) * 8 + j, col = c * 16 + (lane & 15);
        float w = W2[k * 64 + col];
        __bf16 h = (__bf16)w;
        f2h[idx] = h; f2l[idx] = (__bf16)(w - (float)h);
    }
}

// ---------------------------------------------------------------------------
// Split-bf16 MFMA GEMM, m97-style: A staged to LDS via global_load_lds(16B),
// double-buffered 64x64 fp32 chunks, seg-rotation swizzle (seg'=(seg+row)&15)
// for conflict-free ds_reads. B from fragment-ordered global (L1-hot).
//   D = Ah*Bh + Ah*Bl + Al*Bh  (Al*Bl ~2^-18 dropped);  C *= dinv[row]
// ---------------------------------------------------------------------------
template <int K>
__global__ __launch_bounds__(256) void k_gemm_mfma(const float* __restrict__ A,
                                                   const __bf16* __restrict__ BfH,
                                                   const __bf16* __restrict__ BfL,
                                                   const float* __restrict__ dinv,
                                                   float* __restrict__ C, int nrows) {
    constexpr int KC = 64;                 // k per staged chunk
    constexpr int NCHK = K / KC;           // 4 (K=256) or 1 (K=64)
    constexpr int NCH32 = K / 32;
    __shared__ float As[2][64 * KC];       // 2 x 16 KB

    const int t = threadIdx.x;
    const int wave = t >> 6, lane = t & 63;
    const int m = lane & 15, q = lane >> 4;
    const int row0 = blockIdx.x * 64;

    // ---- staging geometry: issue j covers local rows wave*16+j*4+(lane>>4),
    // LDS 16B-seg = lane&15; global seg rotated: s = (seg - localrow) & 15
    const int s_sub = lane >> 4;            // 0..3
    const int s_seg = lane & 15;

    auto stage = [&](int ch, int buf) {
#pragma unroll
        for (int j = 0; j < 4; j++) {
            int lr = wave * 16 + j * 4 + s_sub;               // local row 0..63
            int gr = row0 + lr; if (gr > nrows - 1) gr = nrows - 1;
            int gs = (s_seg - lr) & 15;                       // rotated seg
            const float* g = A + (size_t)gr * K + ch * KC + gs * 4;
            float* l = &As[buf][(size_t)lr * KC + s_seg * 4];
            __builtin_amdgcn_global_load_lds(
                (const __attribute__((address_space(1))) void*)g,
                (__attribute__((address_space(3))) void*)l, 16, 0, 0);
        }
    };

    floatx4 acc[4] = {{0.f, 0.f, 0.f, 0.f}, {0.f, 0.f, 0.f, 0.f},
                      {0.f, 0.f, 0.f, 0.f}, {0.f, 0.f, 0.f, 0.f}};

    stage(0, 0);
    __syncthreads();

    for (int ch = 0; ch < NCHK; ch++) {
        if (ch + 1 < NCHK) stage(ch + 1, (ch + 1) & 1);

        const float* arow = &As[ch & 1][(size_t)(wave * 16 + m) * KC];
#pragma unroll
        for (int jj = 0; jj < 2; jj++) {
            int ch2 = ch * 2 + jj;
            int s0 = jj * 8 + q * 2;                           // wanted seg
            float4 v0 = *(const float4*)(arow + (((s0 + m) & 15) * 4));
            float4 v1 = *(const float4*)(arow + (((s0 + 1 + m) & 15) * 4));
            float af[8] = {v0.x, v0.y, v0.z, v0.w, v1.x, v1.y, v1.z, v1.w};
            bf16x8 ah, al;
#pragma unroll
            for (int j = 0; j < 8; j++) {
                __bf16 h = (__bf16)af[j];
                ah[j] = h;
                al[j] = (__bf16)(af[j] - (float)h);
            }
#pragma unroll
            for (int c = 0; c < 4; c++) {
                const bf16x8 bh = *(const bf16x8*)(BfH + ((size_t)(c * NCH32 + ch2) * 64 + lane) * 8);
                const bf16x8 bl = *(const bf16x8*)(BfL + ((size_t)(c * NCH32 + ch2) * 64 + lane) * 8);
                acc[c] = __builtin_amdgcn_mfma_f32_16x16x32_bf16(ah, bh, acc[c], 0, 0, 0);
                acc[c] = __builtin_amdgcn_mfma_f32_16x16x32_bf16(al, bh, acc[c], 0, 0, 0);
                acc[c] = __builtin_amdgcn_mfma_f32_16x16x32_bf16(ah, bl, acc[c], 0, 0, 0);
            }
        }
        __syncthreads();
    }

#pragma unroll
    for (int i = 0; i < 4; i++) {
        int r = row0 + wave * 16 + q * 4 + i;
        if (r < nrows) {
            float di = dinv[r];
#pragma unroll
            for (int c = 0; c < 4; c++)
                C[(size_t)r * 64 + c * 16 + m] = acc[c][i] * di;
        }
    }
}

// ---------------------------------------------------------------------------
// Aggregation over CSR, 64 features, one wave per node, 8-deep MLP.
// ---------------------------------------------------------------------------
template <int MODE>
__global__ __launch_bounds__(256) void k_agg64(const float* __restrict__ hs,
                                               const float* __restrict__ dinv,
                                               const int* __restrict__ rp,
                                               const int* __restrict__ esrc,
                                               const float* __restrict__ bias,
                                               const float* __restrict__ W3,
                                               float* __restrict__ out, int n) {
    int lane = threadIdx.x & 63;
    int nid = blockIdx.x * 4 + (threadIdx.x >> 6);
    if (nid >= n) return;
    nid = __builtin_amdgcn_readfirstlane(nid);

    float dii = dinv[nid];
    int e0 = rp[nid];
    int e1 = rp[nid + 1];

    float a0 = hs[(size_t)nid * 64 + lane];
    float a1 = 0.f, a2 = 0.f, a3 = 0.f, a4 = 0.f, a5 = 0.f, a6 = 0.f, a7 = 0.f;

    for (int e = e0; e < e1; e += 8) {
        int last = e1 - 1;
        int i0 = esrc[e];
        int i1 = esrc[min(e + 1, last)];
        int i2 = esrc[min(e + 2, last)];
        int i3 = esrc[min(e + 3, last)];
        int i4 = esrc[min(e + 4, last)];
        int i5 = esrc[min(e + 5, last)];
        int i6 = esrc[min(e + 6, last)];
        int i7 = esrc[min(e + 7, last)];
        float v0 = hs[(size_t)i0 * 64 + lane];
        float v1 = hs[(size_t)i1 * 64 + lane];
        float v2 = hs[(size_t)i2 * 64 + lane];
        float v3 = hs[(size_t)i3 * 64 + lane];
        float v4 = hs[(size_t)i4 * 64 + lane];
        float v5 = hs[(size_t)i5 * 64 + lane];
        float v6 = hs[(size_t)i6 * 64 + lane];
        float v7 = hs[(size_t)i7 * 64 + lane];
        a0 += v0;
        a1 += (e + 1 <= last) ? v1 : 0.f;
        a2 += (e + 2 <= last) ? v2 : 0.f;
        a3 += (e + 3 <= last) ? v3 : 0.f;
        a4 += (e + 4 <= last) ? v4 : 0.f;
        a5 += (e + 5 <= last) ? v5 : 0.f;
        a6 += (e + 6 <= last) ? v6 : 0.f;
        a7 += (e + 7 <= last) ? v7 : 0.f;
    }

    float acc = ((a0 + a1) + (a2 + a3)) + ((a4 + a5) + (a6 + a7));
    acc = acc * dii + bias[lane];
    acc = fmaxf(acc, 0.f);

    if (MODE == 0) {
        out[(size_t)nid * 64 + lane] = acc;
    } else {
        float2 w3 = ((const float2*)W3)[lane];
        float p0 = acc * w3.x;
        float p1 = acc * w3.y;
#pragma unroll
        for (int o = 32; o > 0; o >>= 1) {
            p0 += __shfl_xor(p0, o, 64);
            p1 += __shfl_xor(p1, o, 64);
        }
        if (lane == 0) ((float2*)out)[nid] = make_float2(p0 * dii, p1 * dii);
    }
}

// ---------------------------------------------------------------------------
// Final layer: 2-wide aggregation + bias + log_softmax (thread per node)
// ---------------------------------------------------------------------------
__global__ __launch_bounds__(256) void k_final(const float2* __restrict__ h3s,
                                               const float* __restrict__ dinv,
                                               const int* __restrict__ rp,
                                               const int* __restrict__ esrc,
                                               const float* __restrict__ b3,
                                               float* __restrict__ out, int n) {
    int i = blockIdx.x * blockDim.x + threadIdx.x;
    if (i >= n) return;
    float dii = dinv[i];
    float2 h = h3s[i];
    float ax = h.x, ay = h.y;
    float bx = 0.f, by = 0.f, cx = 0.f, cy = 0.f, dx = 0.f, dy = 0.f;
    int e0 = rp[i], e1 = rp[i + 1];
    for (int e = e0; e < e1; e += 4) {
        int last = e1 - 1;
        int s0 = esrc[e];
        int s1 = esrc[min(e + 1, last)];
        int s2 = esrc[min(e + 2, last)];
        int s3 = esrc[min(e + 3, last)];
        float2 v0 = h3s[s0];
        float2 v1 = h3s[s1];
        float2 v2 = h3s[s2];
        float2 v3 = h3s[s3];
        ax += v0.x; ay += v0.y;
        bx += (e + 1 <= last) ? v1.x : 0.f; by += (e + 1 <= last) ? v1.y : 0.f;
        cx += (e + 2 <= last) ? v2.x : 0.f; cy += (e + 2 <= last) ? v2.y : 0.f;
        dx += (e + 3 <= last) ? v3.x : 0.f; dy += (e + 3 <= last) ? v3.y : 0.f;
    }
    float l0 = ((ax + bx) + (cx + dx)) * dii + b3[0];
    float l1 = ((ay + by) + (cy + dy)) * dii + b3[1];
    float m = fmaxf(l0, l1);
    float lse = m + logf(expf(l0 - m) + expf(l1 - m));
    ((float2*)out)[i] = make_float2(l0 - lse, l1 - lse);
}

// ---------------------------------------------------------------------------
// Launch
// ---------------------------------------------------------------------------
extern "C" void kernel_launch(void* const* d_in, const int* in_sizes, int n_in,
                              void* d_out, int out_size, void* d_ws, size_t ws_size,
                              hipStream_t stream) {
    const float* x   = (const float*)d_in[0];
    const int*   ei  = (const int*)d_in[1];
    const float* W1  = (const float*)d_in[2];
    const float* b1  = (const float*)d_in[3];
    const float* W2  = (const float*)d_in[4];
    const float* b2  = (const float*)d_in[5];
    const float* W3  = (const float*)d_in[6];
    const float* b3  = (const float*)d_in[7];
    float* out = (float*)d_out;

    const int N = in_sizes[0] / F_IN;   // 100000
    const int E = in_sizes[1] / 2;      // 1600000
    const int* src = ei;
    const int* dst = ei + E;

    const int NBK = (N + BSPAN - 1) / BSPAN;      // 391
    const int NCH = (E + CHUNK - 1) / CHUNK;      // 98
    const int S   = NBK * NCH;

    // workspace bump allocator (256B aligned)
    char* p = (char*)d_ws;
    auto alloc = [&](size_t bytes) -> void* {
        void* r = (void*)p;
        p += (bytes + 255) & ~(size_t)255;
        return r;
    };
    int*    cntT     = (int*)alloc((size_t)S * 4);
    int*    off      = (int*)alloc((size_t)(S + 1) * 4);
    int*    partials = (int*)alloc(4096);
    int*    ebuf     = (int*)alloc((size_t)E * 4);
    int*    esrc     = (int*)alloc((size_t)E * 4);
    int*    rp       = (int*)alloc((size_t)(N + 1) * 4);
    float*  dinv     = (float*)alloc((size_t)N * 4);
    float*  bufA     = (float*)alloc((size_t)N * HID * 4);
    float*  bufB     = (float*)alloc((size_t)N * HID * 4);
    float*  h3       = (float*)alloc((size_t)N * 2 * 4);
    __bf16* f1h      = (__bf16*)alloc(16384 * 2);
    __bf16* f1l      = (__bf16*)alloc(16384 * 2);
    __bf16* f2h      = (__bf16*)alloc(4096 * 2);
    __bf16* f2l      = (__bf16*)alloc(4096 * 2);

    const int T = 256;
    int scanBlocks = (S + 1023) / 1024;

    // weight prep (independent of CSR chain)
    k_prepw<<<8, T, 0, stream>>>(W1, f1h, f1l, W2, f2h, f2l);

    // CSR build via locality-aware counting sort
    k_hist<<<NCH, T, 0, stream>>>(dst, cntT, E, NCH, NBK);
    k_scanA<<<scanBlocks, T, 0, stream>>>(cntT, off, partials, S);
    k_scanB<<<1, 64, 0, stream>>>(partials, off, scanBlocks, S);
    k_scanC<<<(S + T - 1) / T, T, 0, stream>>>(off, partials, S);
    k_sortwrite<<<NCH, T, 0, stream>>>(src, dst, off, ebuf, E, NCH, NBK);
    k_bucket_csr<<<NBK, T, 0, stream>>>(off, ebuf, rp, dinv, esrc, N, NCH, NBK);

    // layer 1
    int gemmBlocks = (N + 63) / 64;
    k_gemm_mfma<F_IN><<<gemmBlocks, T, 0, stream>>>(x, f1h, f1l, dinv, bufA, N);
    k_agg64<0><<<(N + 3) / 4, T, 0, stream>>>(bufA, dinv, rp, esrc, b1, nullptr, bufB, N);

    // layer 2 (+ fused GEMM3)
    k_gemm_mfma<HID><<<gemmBlocks, T, 0, stream>>>(bufB, f2h, f2l, dinv, bufA, N);
    k_agg64<1><<<(N + 3) / 4, T, 0, stream>>>(bufA, dinv, rp, esrc, b2, W3, h3, N);

    // layer 3 + log_softmax
    k_final<<<(N + T - 1) / T, T, 0, stream>>>((const float2*)h3, dinv, rp, esrc, b3, out, N);
}

// Round 8
// 404.414 us; speedup vs baseline: 1.1402x; 1.0259x over previous
//
#include <hip/hip_runtime.h>
#include <math.h>

#define F_IN 256
#define HID  64
#define BSH  8              // bucket = dst >> 8 (256 nodes per bucket)
#define BSPAN 256
#define CHUNK 16384         // edges per sort block (64 per thread)
#define NBK_MAX 512

typedef __bf16   bf16x8 __attribute__((ext_vector_type(8)));
typedef float    floatx4 __attribute__((ext_vector_type(4)));
typedef _Float16 half8 __attribute__((ext_vector_type(8)));

// ---------------------------------------------------------------------------
// Pass 1: per-chunk histogram over coarse dst buckets
// ---------------------------------------------------------------------------
__global__ __launch_bounds__(256) void k_hist(const int* __restrict__ dst,
                                              int* __restrict__ cntT,
                                              int E, int NCH, int NBK) {
    __shared__ int hist[NBK_MAX];
    int t = threadIdx.x, c = blockIdx.x;
    hist[t] = 0; hist[t + 256] = 0;
    __syncthreads();
    int base = c * CHUNK;
#pragma unroll 4
    for (int j = 0; j < CHUNK / 256; j++) {
        int e = base + j * 256 + t;
        if (e < E) atomicAdd(&hist[dst[e] >> BSH], 1);
    }
    __syncthreads();
    for (int b = t; b < NBK; b += 256) cntT[b * NCH + c] = hist[b];
}

// ---------------------------------------------------------------------------
// Exclusive scan of cntT (S elements) -> off, plus sentinel off[S] = total
// ---------------------------------------------------------------------------
__global__ __launch_bounds__(256) void k_scanA(const int* __restrict__ cntT,
                                               int* __restrict__ off,
                                               int* __restrict__ partials, int S) {
    __shared__ int sh[256];
    int tid = threadIdx.x;
    int base = blockIdx.x * 1024 + tid * 4;
    int v[4];
    int s = 0;
#pragma unroll
    for (int j = 0; j < 4; j++) {
        int idx = base + j;
        v[j] = (idx < S) ? cntT[idx] : 0;
        s += v[j];
    }
    sh[tid] = s;
    __syncthreads();
    int mysum = s;
    for (int o = 1; o < 256; o <<= 1) {
        int tv = (tid >= o) ? sh[tid - o] : 0;
        __syncthreads();
        sh[tid] += tv;
        __syncthreads();
    }
    int pref = sh[tid] - mysum;
#pragma unroll
    for (int j = 0; j < 4; j++) {
        int idx = base + j;
        if (idx < S) off[idx] = pref;
        pref += v[j];
    }
    if (tid == 255) partials[blockIdx.x] = sh[255];
}

__global__ void k_scanB(int* __restrict__ partials, int* __restrict__ off,
                        int nblk, int S) {
    if (blockIdx.x == 0 && threadIdx.x == 0) {
        int run = 0;
        for (int b = 0; b < nblk; b++) { int t = partials[b]; partials[b] = run; run += t; }
        off[S] = run;   // == E
    }
}

__global__ void k_scanC(int* __restrict__ off, const int* __restrict__ partials, int S) {
    int i = blockIdx.x * blockDim.x + threadIdx.x;
    if (i < S) off[i] += partials[i >> 10];
}

// ---------------------------------------------------------------------------
// Pass 2: scatter edges into bucket-grouped ebuf. Entry = (src<<8)|(dst&255)
// ---------------------------------------------------------------------------
__global__ __launch_bounds__(256) void k_sortwrite(const int* __restrict__ src,
                                                   const int* __restrict__ dst,
                                                   const int* __restrict__ off,
                                                   int* __restrict__ ebuf,
                                                   int E, int NCH, int NBK) {
    __shared__ int cur[NBK_MAX];
    int t = threadIdx.x, c = blockIdx.x;
    for (int b = t; b < NBK; b += 256) cur[b] = off[b * NCH + c];
    __syncthreads();
    int base = c * CHUNK;
#pragma unroll 4
    for (int j = 0; j < CHUNK / 256; j++) {
        int e = base + j * 256 + t;
        if (e < E) {
            int s = src[e];
            int d = dst[e];
            int pos = atomicAdd(&cur[d >> BSH], 1);
            ebuf[pos] = (s << BSH) | (d & (BSPAN - 1));
        }
    }
}

// ---------------------------------------------------------------------------
// Pass 3: per-bucket node-level CSR: rp, dinv, node-sorted esrc
// ---------------------------------------------------------------------------
__global__ __launch_bounds__(256) void k_bucket_csr(const int* __restrict__ off,
                                                    const int* __restrict__ ebuf,
                                                    int* __restrict__ rp,
                                                    float* __restrict__ dinv,
                                                    int* __restrict__ esrc,
                                                    int N, int NCH, int NBK) {
    __shared__ int cnt[BSPAN];
    __shared__ int sh[BSPAN];
    int b = blockIdx.x, t = threadIdx.x;
    int base = off[b * NCH];
    int end  = off[(b + 1) * NCH];

    cnt[t] = 0;
    __syncthreads();
    for (int i = base + t; i < end; i += 256) atomicAdd(&cnt[ebuf[i] & (BSPAN - 1)], 1);
    __syncthreads();

    int c = cnt[t];
    sh[t] = c;
    __syncthreads();
    for (int o = 1; o < 256; o <<= 1) {
        int tv = (t >= o) ? sh[t - o] : 0;
        __syncthreads();
        sh[t] += tv;
        __syncthreads();
    }
    int excl = sh[t] - c;

    int node = (b << BSH) + t;
    if (node < N) {
        rp[node] = base + excl;
        dinv[node] = rsqrtf((float)(1 + c));
    }
    if (b == NBK - 1 && t == 0) rp[N] = end;
    __syncthreads();

    cnt[t] = base + excl;
    __syncthreads();
    for (int i = base + t; i < end; i += 256) {
        int v = ebuf[i];
        int p = atomicAdd(&cnt[v & (BSPAN - 1)], 1);
        esrc[p] = v >> BSH;
    }
}

// ---------------------------------------------------------------------------
// Weight prep: W[K x 64] -> split-bf16 MFMA FRAGMENT layout
//   Bf[c][ch2][lane][j] = W[ch2*32 + (lane>>4)*8 + j][c*16 + (lane&15)]
// ---------------------------------------------------------------------------
__global__ __launch_bounds__(256) void k_prepw(const float* __restrict__ W1,
                                               __bf16* __restrict__ f1h, __bf16* __restrict__ f1l,
                                               const float* __restrict__ W2,
                                               __bf16* __restrict__ f2h, __bf16* __restrict__ f2l) {
    int t = threadIdx.x + blockIdx.x * blockDim.x;   // 2048 threads
    for (int idx = t; idx < 16384; idx += 2048) {
        int j = idx & 7, lane = (idx >> 3) & 63, ch2 = (idx >> 9) & 7, c = idx >> 12;
        int k = ch2 * 32 + (lane >> 4) * 8 + j, col = c * 16 + (lane & 15);
        float w = W1[k * 64 + col];
        __bf16 h = (__bf16)w;
        f1h[idx] = h; f1l[idx] = (__bf16)(w - (float)h);
    }
    for (int idx = t; idx < 4096; idx += 2048) {
        int j = idx & 7, lane = (idx >> 3) & 63, ch2 = (idx >> 9) & 1, c = idx >> 10;
        int k = ch2 * 32 + (lane >> 4) * 8 + j, col = c * 16 + (lane & 15);
        float w = W2[k * 64 + col];
        __bf16 h = (__bf16)w;
        f2h[idx] = h; f2l[idx] = (__bf16)(w - (float)h);
    }
}

// ---------------------------------------------------------------------------
// GEMM1 (K=256, A fp32): m97-style LDS staging via global_load_lds(16B),
// double-buffered 64x64 chunks, seg-rotation swizzle. Output fp16.
//   D = Ah*Bh + Ah*Bl + Al*Bh;  C = D * dinv[row]  (fp16 store)
// ---------------------------------------------------------------------------
__global__ __launch_bounds__(256) void k_gemm1(const float* __restrict__ A,
                                               const __bf16* __restrict__ BfH,
                                               const __bf16* __restrict__ BfL,
                                               const float* __restrict__ dinv,
                                               _Float16* __restrict__ C, int nrows) {
    constexpr int K = 256, KC = 64, NCHK = 4, NCH32 = 8;
    __shared__ float As[2][64 * KC];       // 2 x 16 KB

    const int t = threadIdx.x;
    const int wave = t >> 6, lane = t & 63;
    const int m = lane & 15, q = lane >> 4;
    const int row0 = blockIdx.x * 64;

    const int s_sub = lane >> 4;
    const int s_seg = lane & 15;

    auto stage = [&](int ch, int buf) {
#pragma unroll
        for (int j = 0; j < 4; j++) {
            int lr = wave * 16 + j * 4 + s_sub;
            int gr = row0 + lr; if (gr > nrows - 1) gr = nrows - 1;
            int gs = (s_seg - lr) & 15;
            const float* g = A + (size_t)gr * K + ch * KC + gs * 4;
            float* l = &As[buf][(size_t)lr * KC + s_seg * 4];
            __builtin_amdgcn_global_load_lds(
                (const __attribute__((address_space(1))) void*)g,
                (__attribute__((address_space(3))) void*)l, 16, 0, 0);
        }
    };

    floatx4 acc[4] = {{0.f, 0.f, 0.f, 0.f}, {0.f, 0.f, 0.f, 0.f},
                      {0.f, 0.f, 0.f, 0.f}, {0.f, 0.f, 0.f, 0.f}};

    stage(0, 0);
    __syncthreads();

    for (int ch = 0; ch < NCHK; ch++) {
        if (ch + 1 < NCHK) stage(ch + 1, (ch + 1) & 1);

        const float* arow = &As[ch & 1][(size_t)(wave * 16 + m) * KC];
#pragma unroll
        for (int jj = 0; jj < 2; jj++) {
            int ch2 = ch * 2 + jj;
            int s0 = jj * 8 + q * 2;
            float4 v0 = *(const float4*)(arow + (((s0 + m) & 15) * 4));
            float4 v1 = *(const float4*)(arow + (((s0 + 1 + m) & 15) * 4));
            float af[8] = {v0.x, v0.y, v0.z, v0.w, v1.x, v1.y, v1.z, v1.w};
            bf16x8 ah, al;
#pragma unroll
            for (int j = 0; j < 8; j++) {
                __bf16 h = (__bf16)af[j];
                ah[j] = h;
                al[j] = (__bf16)(af[j] - (float)h);
            }
#pragma unroll
            for (int c = 0; c < 4; c++) {
                const bf16x8 bh = *(const bf16x8*)(BfH + ((size_t)(c * NCH32 + ch2) * 64 + lane) * 8);
                const bf16x8 bl = *(const bf16x8*)(BfL + ((size_t)(c * NCH32 + ch2) * 64 + lane) * 8);
                acc[c] = __builtin_amdgcn_mfma_f32_16x16x32_bf16(ah, bh, acc[c], 0, 0, 0);
                acc[c] = __builtin_amdgcn_mfma_f32_16x16x32_bf16(al, bh, acc[c], 0, 0, 0);
                acc[c] = __builtin_amdgcn_mfma_f32_16x16x32_bf16(ah, bl, acc[c], 0, 0, 0);
            }
        }
        __syncthreads();
    }

#pragma unroll
    for (int i = 0; i < 4; i++) {
        int r = row0 + wave * 16 + q * 4 + i;
        if (r < nrows) {
            float di = dinv[r];
#pragma unroll
            for (int c = 0; c < 4; c++)
                C[(size_t)r * 64 + c * 16 + m] = (_Float16)(acc[c][i] * di);
        }
    }
}

// ---------------------------------------------------------------------------
// GEMM2 (K=64, A fp16): single 8 KB LDS stage (8 segs/row, seg-rotated),
// same split-bf16 MFMA math. Output fp16.
// ---------------------------------------------------------------------------
__global__ __launch_bounds__(256) void k_gemm2(const _Float16* __restrict__ A,
                                               const __bf16* __restrict__ BfH,
                                               const __bf16* __restrict__ BfL,
                                               const float* __restrict__ dinv,
                                               _Float16* __restrict__ C, int nrows) {
    __shared__ _Float16 As[64 * 64];       // 8 KB
    const int t = threadIdx.x;
    const int wave = t >> 6, lane = t & 63;
    const int m = lane & 15, q = lane >> 4;
    const int row0 = blockIdx.x * 64;

    // stage: issue j covers rows j*32 + wave*8 + (lane>>3); pos p = lane&7
    // LDS dest = wavebase + lane*16 (contiguous in lane order) ✓
#pragma unroll
    for (int j = 0; j < 2; j++) {
        int lr = j * 32 + wave * 8 + (lane >> 3);
        int p  = lane & 7;
        int gr = row0 + lr; if (gr > nrows - 1) gr = nrows - 1;
        int gs = (p - lr) & 7;                          // rotated seg
        const _Float16* g = A + (size_t)gr * 64 + gs * 8;
        _Float16* l = &As[(size_t)lr * 64 + p * 8];
        __builtin_amdgcn_global_load_lds(
            (const __attribute__((address_space(1))) void*)g,
            (__attribute__((address_space(3))) void*)l, 16, 0, 0);
    }
    __syncthreads();

    floatx4 acc[4] = {{0.f, 0.f, 0.f, 0.f}, {0.f, 0.f, 0.f, 0.f},
                      {0.f, 0.f, 0.f, 0.f}, {0.f, 0.f, 0.f, 0.f}};

    const _Float16* arow = &As[(size_t)(wave * 16 + m) * 64];
#pragma unroll
    for (int jj = 0; jj < 2; jj++) {
        int s0 = jj * 4 + q;
        half8 v = *(const half8*)(arow + (((s0 + m) & 7) * 8));
        bf16x8 ah, al;
#pragma unroll
        for (int j = 0; j < 8; j++) {
            float f = (float)v[j];
            __bf16 h = (__bf16)f;
            ah[j] = h;
            al[j] = (__bf16)(f - (float)h);
        }
#pragma unroll
        for (int c = 0; c < 4; c++) {
            const bf16x8 bh = *(const bf16x8*)(BfH + ((size_t)(c * 2 + jj) * 64 + lane) * 8);
            const bf16x8 bl = *(const bf16x8*)(BfL + ((size_t)(c * 2 + jj) * 64 + lane) * 8);
            acc[c] = __builtin_amdgcn_mfma_f32_16x16x32_bf16(ah, bh, acc[c], 0, 0, 0);
            acc[c] = __builtin_amdgcn_mfma_f32_16x16x32_bf16(al, bh, acc[c], 0, 0, 0);
            acc[c] = __builtin_amdgcn_mfma_f32_16x16x32_bf16(ah, bl, acc[c], 0, 0, 0);
        }
    }

#pragma unroll
    for (int i = 0; i < 4; i++) {
        int r = row0 + wave * 16 + q * 4 + i;
        if (r < nrows) {
            float di = dinv[r];
#pragma unroll
            for (int c = 0; c < 4; c++)
                C[(size_t)r * 64 + c * 16 + m] = (_Float16)(acc[c][i] * di);
        }
    }
}

// ---------------------------------------------------------------------------
// Aggregation over CSR, 64 features fp16, one wave per node, 8-deep MLP.
// fp32 accumulate.  v = relu(dinv[d]*(hs[d]+sum hs[src])+bias)
// MODE 0: out[d] = v (fp16)   MODE 1: h3[d] = (v @ W3) * dinv[d] (fp32)
// ---------------------------------------------------------------------------
template <int MODE>
__global__ __launch_bounds__(256) void k_agg64(const _Float16* __restrict__ hs,
                                               const float* __restrict__ dinv,
                                               const int* __restrict__ rp,
                                               const int* __restrict__ esrc,
                                               const float* __restrict__ bias,
                                               const float* __restrict__ W3,
                                               void* __restrict__ out, int n) {
    int lane = threadIdx.x & 63;
    int nid = blockIdx.x * 4 + (threadIdx.x >> 6);
    if (nid >= n) return;
    nid = __builtin_amdgcn_readfirstlane(nid);

    float dii = dinv[nid];
    int e0 = rp[nid];
    int e1 = rp[nid + 1];

    float a0 = (float)hs[(size_t)nid * 64 + lane];
    float a1 = 0.f, a2 = 0.f, a3 = 0.f, a4 = 0.f, a5 = 0.f, a6 = 0.f, a7 = 0.f;

    for (int e = e0; e < e1; e += 8) {
        int last = e1 - 1;
        int i0 = esrc[e];
        int i1 = esrc[min(e + 1, last)];
        int i2 = esrc[min(e + 2, last)];
        int i3 = esrc[min(e + 3, last)];
        int i4 = esrc[min(e + 4, last)];
        int i5 = esrc[min(e + 5, last)];
        int i6 = esrc[min(e + 6, last)];
        int i7 = esrc[min(e + 7, last)];
        float v0 = (float)hs[(size_t)i0 * 64 + lane];
        float v1 = (float)hs[(size_t)i1 * 64 + lane];
        float v2 = (float)hs[(size_t)i2 * 64 + lane];
        float v3 = (float)hs[(size_t)i3 * 64 + lane];
        float v4 = (float)hs[(size_t)i4 * 64 + lane];
        float v5 = (float)hs[(size_t)i5 * 64 + lane];
        float v6 = (float)hs[(size_t)i6 * 64 + lane];
        float v7 = (float)hs[(size_t)i7 * 64 + lane];
        a0 += v0;
        a1 += (e + 1 <= last) ? v1 : 0.f;
        a2 += (e + 2 <= last) ? v2 : 0.f;
        a3 += (e + 3 <= last) ? v3 : 0.f;
        a4 += (e + 4 <= last) ? v4 : 0.f;
        a5 += (e + 5 <= last) ? v5 : 0.f;
        a6 += (e + 6 <= last) ? v6 : 0.f;
        a7 += (e + 7 <= last) ? v7 : 0.f;
    }

    float acc = ((a0 + a1) + (a2 + a3)) + ((a4 + a5) + (a6 + a7));
    acc = acc * dii + bias[lane];
    acc = fmaxf(acc, 0.f);

    if (MODE == 0) {
        ((_Float16*)out)[(size_t)nid * 64 + lane] = (_Float16)acc;
    } else {
        float2 w3 = ((const float2*)W3)[lane];
        float p0 = acc * w3.x;
        float p1 = acc * w3.y;
#pragma unroll
        for (int o = 32; o > 0; o >>= 1) {
            p0 += __shfl_xor(p0, o, 64);
            p1 += __shfl_xor(p1, o, 64);
        }
        if (lane == 0) ((float2*)out)[nid] = make_float2(p0 * dii, p1 * dii);
    }
}

// ---------------------------------------------------------------------------
// Final layer: 2-wide aggregation + bias + log_softmax (thread per node)
// ---------------------------------------------------------------------------
__global__ __launch_bounds__(256) void k_final(const float2* __restrict__ h3s,
                                               const float* __restrict__ dinv,
                                               const int* __restrict__ rp,
                                               const int* __restrict__ esrc,
                                               const float* __restrict__ b3,
                                               float* __restrict__ out, int n) {
    int i = blockIdx.x * blockDim.x + threadIdx.x;
    if (i >= n) return;
    float dii = dinv[i];
    float2 h = h3s[i];
    float ax = h.x, ay = h.y;
    float bx = 0.f, by = 0.f, cx = 0.f, cy = 0.f, dx = 0.f, dy = 0.f;
    int e0 = rp[i], e1 = rp[i + 1];
    for (int e = e0; e < e1; e += 4) {
        int last = e1 - 1;
        int s0 = esrc[e];
        int s1 = esrc[min(e + 1, last)];
        int s2 = esrc[min(e + 2, last)];
        int s3 = esrc[min(e + 3, last)];
        float2 v0 = h3s[s0];
        float2 v1 = h3s[s1];
        float2 v2 = h3s[s2];
        float2 v3 = h3s[s3];
        ax += v0.x; ay += v0.y;
        bx += (e + 1 <= last) ? v1.x : 0.f; by += (e + 1 <= last) ? v1.y : 0.f;
        cx += (e + 2 <= last) ? v2.x : 0.f; cy += (e + 2 <= last) ? v2.y : 0.f;
        dx += (e + 3 <= last) ? v3.x : 0.f; dy += (e + 3 <= last) ? v3.y : 0.f;
    }
    float l0 = ((ax + bx) + (cx + dx)) * dii + b3[0];
    float l1 = ((ay + by) + (cy + dy)) * dii + b3[1];
    float m = fmaxf(l0, l1);
    float lse = m + logf(expf(l0 - m) + expf(l1 - m));
    ((float2*)out)[i] = make_float2(l0 - lse, l1 - lse);
}

// ---------------------------------------------------------------------------
// Launch
// ---------------------------------------------------------------------------
extern "C" void kernel_launch(void* const* d_in, const int* in_sizes, int n_in,
                              void* d_out, int out_size, void* d_ws, size_t ws_size,
                              hipStream_t stream) {
    const float* x   = (const float*)d_in[0];
    const int*   ei  = (const int*)d_in[1];
    const float* W1  = (const float*)d_in[2];
    const float* b1  = (const float*)d_in[3];
    const float* W2  = (const float*)d_in[4];
    const float* b2  = (const float*)d_in[5];
    const float* W3  = (const float*)d_in[6];
    const float* b3  = (const float*)d_in[7];
    float* out = (float*)d_out;

    const int N = in_sizes[0] / F_IN;   // 100000
    const int E = in_sizes[1] / 2;      // 1600000
    const int* src = ei;
    const int* dst = ei + E;

    const int NBK = (N + BSPAN - 1) / BSPAN;      // 391
    const int NCH = (E + CHUNK - 1) / CHUNK;      // 98
    const int S   = NBK * NCH;

    // workspace bump allocator (256B aligned)
    char* p = (char*)d_ws;
    auto alloc = [&](size_t bytes) -> void* {
        void* r = (void*)p;
        p += (bytes + 255) & ~(size_t)255;
        return r;
    };
    int*      cntT     = (int*)alloc((size_t)S * 4);
    int*      off      = (int*)alloc((size_t)(S + 1) * 4);
    int*      partials = (int*)alloc(4096);
    int*      ebuf     = (int*)alloc((size_t)E * 4);
    int*      esrc     = (int*)alloc((size_t)E * 4);
    int*      rp       = (int*)alloc((size_t)(N + 1) * 4);
    float*    dinv     = (float*)alloc((size_t)N * 4);
    _Float16* bufA     = (_Float16*)alloc((size_t)N * HID * 2);
    _Float16* bufB     = (_Float16*)alloc((size_t)N * HID * 2);
    float*    h3       = (float*)alloc((size_t)N * 2 * 4);
    __bf16*   f1h      = (__bf16*)alloc(16384 * 2);
    __bf16*   f1l      = (__bf16*)alloc(16384 * 2);
    __bf16*   f2h      = (__bf16*)alloc(4096 * 2);
    __bf16*   f2l      = (__bf16*)alloc(4096 * 2);

    const int T = 256;
    int scanBlocks = (S + 1023) / 1024;

    // weight prep (independent of CSR chain)
    k_prepw<<<8, T, 0, stream>>>(W1, f1h, f1l, W2, f2h, f2l);

    // CSR build via locality-aware counting sort
    k_hist<<<NCH, T, 0, stream>>>(dst, cntT, E, NCH, NBK);
    k_scanA<<<scanBlocks, T, 0, stream>>>(cntT, off, partials, S);
    k_scanB<<<1, 64, 0, stream>>>(partials, off, scanBlocks, S);
    k_scanC<<<(S + T - 1) / T, T, 0, stream>>>(off, partials, S);
    k_sortwrite<<<NCH, T, 0, stream>>>(src, dst, off, ebuf, E, NCH, NBK);
    k_bucket_csr<<<NBK, T, 0, stream>>>(off, ebuf, rp, dinv, esrc, N, NCH, NBK);

    // layer 1
    int gemmBlocks = (N + 63) / 64;
    k_gemm1<<<gemmBlocks, T, 0, stream>>>(x, f1h, f1l, dinv, bufA, N);
    k_agg64<0><<<(N + 3) / 4, T, 0, stream>>>(bufA, dinv, rp, esrc, b1, nullptr, bufB, N);

    // layer 2 (+ fused GEMM3)
    k_gemm2<<<gemmBlocks, T, 0, stream>>>(bufB, f2h, f2l, dinv, bufA, N);
    k_agg64<1><<<(N + 3) / 4, T, 0, stream>>>(bufA, dinv, rp, esrc, b2, W3, h3, N);

    // layer 3 + log_softmax
    k_final<<<(N + T - 1) / T, T, 0, stream>>>((const float2*)h3, dinv, rp, esrc, b3, out, N);
}